// Round 11
// baseline (159.885 us; speedup 1.0000x reference)
//
#include <hip/hip_runtime.h>
#include <hip/hip_bf16.h>

// MDTA: prep (dtype probe + param convert + X transpose, ONE kernel) ->
// qkv 1x1 conv (MFMA GEMM 64ox64p, LDS-transposed vectorized bf16 epilogue)
// -> 3x3 depthwise (zero-padded LDS image, b128 reads; V channels written in
// MFMA-fragment order "VT") -> l2norm (K-ONLY -> KT2 fragment order; q-norm
// is fused into flash's Q load) -> flash attention (32x32x16 MFMA,
// 512-thread blocks: 2 q-tiles x 4 K-streams, K/V staged via linear
// global_load_lds DMA (3-buffer ring, counted vmcnt), conflict-free
// stride-1 ds_read_b128, register-resident P via cvt_pk_bf16 +
// permlane32_swap, fixed-max softmax (|q.k|<=1), row-sums free via all-ones
// V column, 4-way additive K-split combine) -> 1x1 proj (MFMA GEMM).
// Input/output dtype probed at runtime; intermediates bf16 in d_ws.

#define BB 2
#define CCH 192
#define C3 576
#define NH 4
#define HD 48
#define NP 4096

typedef __hip_bfloat16 bf16;
typedef __attribute__((ext_vector_type(8))) short bf16x8;
typedef __attribute__((ext_vector_type(4))) float f32x4;
typedef __attribute__((ext_vector_type(16))) float f32x16;

union I4B8 { int4 i; bf16x8 v; };

__device__ inline float bf2f(bf16 v){ return __bfloat162float(v); }
__device__ inline unsigned short f2bfbits(float f){ return __builtin_bit_cast(unsigned short, __float2bfloat16(f)); }
__device__ inline float bfb2f(short s){ return __uint_as_float(((unsigned)(unsigned short)s)<<16); }

// pack two f32 -> dword of two bf16 (lo = first)
__device__ inline unsigned pkbf(float lo, float hi){
  unsigned r;
  asm("v_cvt_pk_bf16_f32 %0, %1, %2" : "=v"(r) : "v"(lo), "v"(hi));
  return r;
}
// swap lanes 0-31 of x with lanes 32-63 of y (both results used)
__device__ inline void plswap(unsigned &x, unsigned &y){
  asm("v_permlane32_swap_b32 %0, %1" : "+v"(x), "+v"(y));
}
// 16B global -> LDS DMA (dest = wave-uniform base + lane*16)
__device__ inline void gl_lds16(const void* g, void* l){
  __builtin_amdgcn_global_load_lds(
      (const __attribute__((address_space(1))) void*)g,
      (__attribute__((address_space(3))) void*)l, 16, 0, 0);
}

// ---------------------------------------------------------------------------
// prep: per-block dtype probe (x[0..255] dwords, L2-hot) + param convert
// (grid-strided across the 384 blocks) + X transpose -> XT [b][4096][192].
// ---------------------------------------------------------------------------
#define NCANON 153988
__global__ __launch_bounds__(256) void prep_kernel(
    const void* __restrict__ Xv,
    const void* w_qkv, const void* b_qkv, const void* w_dw, const void* b_dw,
    const void* w_proj, const void* b_proj, const void* temp,
    int* __restrict__ flag, bf16* __restrict__ canon, short* __restrict__ XT)
{
  __shared__ int cnt;
  __shared__ short T[64][66];
  const int tid = threadIdx.x;
  {
    unsigned u = ((const unsigned*)Xv)[tid];
    int e = (u >> 7) & 0xff;
    int sane = (e >= 100 && e <= 140) || ((u & 0x7fffu) == 0u);
    if (tid == 0) cnt = 0;
    __syncthreads();
    if (sane) atomicAdd(&cnt, 1);
    __syncthreads();
  }
  const bool isbf = (cnt >= 192);
  const int bid = (blockIdx.z*64 + blockIdx.y)*3 + blockIdx.x;   // 0..383
  if (bid == 0 && tid == 0) *flag = isbf ? 1 : 0;

  // param convert, grid-stride (384*256 = 98304 threads, 2 passes)
  for (int i = bid*256 + tid; i < NCANON; i += 384*256){
    const void* src; int off;
    if      (i < 110592){ src = w_qkv;  off = i; }
    else if (i < 111168){ src = b_qkv;  off = i - 110592; }
    else if (i < 116352){ src = w_dw;   off = i - 111168; }
    else if (i < 116928){ src = b_dw;   off = i - 116352; }
    else if (i < 153792){ src = w_proj; off = i - 116928; }
    else if (i < 153984){ src = b_proj; off = i - 153792; }
    else                { src = temp;   off = i - 153984; }
    float v = isbf ? bf2f(((const bf16*)src)[off]) : ((const float*)src)[off];
    canon[i] = __float2bfloat16(v);
  }

  // transpose X tile
  const int c0 = blockIdx.x*64, p0 = blockIdx.y*64, b = blockIdx.z;
  const size_t xbase = (size_t)b*CCH*NP;
  #pragma unroll
  for (int s=0;s<16;s++){
    int i = tid + s*256;
    int cc = i>>6, pp = i&63;
    size_t g = xbase + (size_t)(c0+cc)*NP + p0+pp;
    float v = isbf ? bf2f(((const bf16*)Xv)[g]) : ((const float*)Xv)[g];
    T[cc][pp] = (short)f2bfbits(v);
  }
  __syncthreads();
  #pragma unroll
  for (int s=0;s<16;s++){
    int i = tid + s*256;
    int pl = i>>6, cl = i&63;
    XT[((size_t)b*NP + p0+pl)*CCH + c0+cl] = T[cl][pl];
  }
}

// ---------------------------------------------------------------------------
// 1x1 conv as MFMA GEMM.  Block 64o x 64p, 4 waves (wave = 16p x 64o).
// Smaller p-tile doubles grid size: qkv 1152 blocks (4.5/CU), proj 384
// (1.5/CU) - kills the sub-occupancy tail of the old 128p version.
// bf16 output: acc transposed through the (dead) Bs tile -> 2 coalesced
// int4 stores/thread.
// ---------------------------------------------------------------------------
__global__ __launch_bounds__(256) void conv1x1_mfma_kernel(
    const int* __restrict__ flag, int ydyn,
    const short* __restrict__ XT,      // [b][4096][192] bf16 bits
    const bf16* __restrict__ Wt,       // [OC][192]
    const bf16* __restrict__ bias,
    void* __restrict__ Yv, int OC)
{
  const bool yf32 = ydyn && (*flag == 0);
  __shared__ __align__(16) short Bs[2][64*32];   // 8 KB
  const int tid = threadIdx.x, wave = tid>>6, lane = tid&63;
  const int l16 = lane&15, quad = lane>>4;
  const int o0 = blockIdx.x*64, p0 = blockIdx.y*64, b = blockIdx.z;
  const short* XTb = XT + ((size_t)b*NP + p0)*CCH;
  const short* Wb  = (const short*)Wt;

  f32x4 acc[4];
  #pragma unroll
  for (int mt=0;mt<4;mt++)
    #pragma unroll
    for (int r=0;r<4;r++)
      acc[mt][r] = bf2f(bias[o0+mt*16+quad*4+r]);

  int4 sreg;
  I4B8 Afr[2][4];
  #define CLOAD(kc) { sreg = *(const int4*)&XTb[(size_t)(tid>>2)*CCH + (kc)*32 + (tid&3)*8]; }
  #define CSTORE(buf) { *(int4*)&Bs[buf][(tid>>2)*32 + (tid&3)*8] = sreg; }
  #define ALOAD(kc, buf) { _Pragma("unroll") for (int mt_=0;mt_<4;mt_++){ \
      Afr[buf][mt_].i = *(const int4*)&Wb[(size_t)(o0+mt_*16+l16)*CCH + (kc)*32 + quad*8]; } }

  CLOAD(0); CSTORE(0); ALOAD(0,0);
  __syncthreads();

  #pragma unroll
  for (int kc=0; kc<6; kc++){
    const int cur = kc&1;
    if (kc<5){ CLOAD(kc+1); ALOAD(kc+1, cur^1); }
    I4B8 Bf;
    Bf.i = *(const int4*)&Bs[cur][(wave*16 + l16)*32 + quad*8];
    #pragma unroll
    for (int mt=0;mt<4;mt++)
      acc[mt] = __builtin_amdgcn_mfma_f32_16x16x32_bf16(Afr[cur][mt].v, Bf.v, acc[mt], 0,0,0);
    if (kc<5) CSTORE(cur^1);
    __syncthreads();
  }
  #undef CLOAD
  #undef CSTORE
  #undef ALOAD

  if (yf32){
    #pragma unroll
    for (int mt=0;mt<4;mt++)
      #pragma unroll
      for (int r=0;r<4;r++){
        int o = o0 + mt*16 + quad*4 + r;
        int p = p0 + wave*16 + l16;
        ((float*)Yv)[((size_t)b*OC + o)*NP + p] = acc[mt][r];
      }
  } else {
    short* Os = &Bs[0][0];                  // 64 x 64 bf16 tile (Bs dead)
    #pragma unroll
    for (int mt=0;mt<4;mt++)
      #pragma unroll
      for (int r=0;r<4;r++)
        Os[(mt*16+quad*4+r)*64 + wave*16 + l16] = (short)f2bfbits(acc[mt][r]);
    __syncthreads();
    const int o = tid>>2, xs = tid&3;
    bf16* dst = (bf16*)Yv + ((size_t)b*OC + o0 + o)*NP + p0 + xs*16;
    *(int4*)(dst)     = *(int4*)&Os[o*64 + xs*16];
    *(int4*)(dst + 8) = *(int4*)&Os[o*64 + xs*16 + 8];
  }
}

// ---------------------------------------------------------------------------
// 3x3 depthwise conv, padding 1. One block per (b,ch) image.
// Zero-padded LDS image [66][88] (data at [y+1][8+x]); b128 reads; no
// bounds branches. q/k channels (ch < 384): linear write. V channels:
// MFMA-fragment order VT (see R9 comment).
// ---------------------------------------------------------------------------
__global__ __launch_bounds__(256) void dwconv_kernel(
    const bf16* __restrict__ in, const bf16* __restrict__ w,
    const bf16* __restrict__ bias, bf16* __restrict__ out)
{
  __shared__ __align__(16) short img[66*88];   // 11616 B = 726 int4, padded
  const int bc = blockIdx.x; const int ch = bc % C3; const int b = bc / C3;
  const int tid = threadIdx.x;
  {
    int4 zz = {0,0,0,0};
    int4* s4 = (int4*)img;                     // 726 int4 total
    s4[tid] = zz;
    s4[tid+256] = zz;
    if (tid < 214) s4[tid+512] = zz;
  }
  float wv[9];
  #pragma unroll
  for (int j=0;j<9;j++) wv[j] = bf2f(w[ch*9+j]);
  const float bv = bf2f(bias[ch]);
  __syncthreads();
  {
    const int4* g4 = (const int4*)(in + (size_t)bc*NP);
    int i = tid;      int y = i>>3, u = i&7;
    *(int4*)&img[(y+1)*88 + 8 + u*8] = g4[i];
    i = tid+256;      y = i>>3;  u = i&7;
    *(int4*)&img[(y+1)*88 + 8 + u*8] = g4[i];
  }
  __syncthreads();

  const int yp = tid>>3, xs = tid&7, x0 = xs*8;   // rows 2yp,2yp+1; cols x0..x0+7
  float f[4][10];
  #pragma unroll
  for (int r=0;r<4;r++){
    const int base = (2*yp + r)*88 + x0;          // data col x0-8 at this addr
    short t[24];
    *(int4*)&t[0]  = *(const int4*)&img[base];
    *(int4*)&t[8]  = *(const int4*)&img[base+8];
    *(int4*)&t[16] = *(const int4*)&img[base+16];
    #pragma unroll
    for (int c=0;c<10;c++) f[r][c] = bfb2f(t[7+c]);  // data cols x0-1 .. x0+8
  }
  unsigned ow0[4], ow1[4];
  #pragma unroll
  for (int j=0;j<8;j++){
    float s0 = bv, s1 = bv;
    #pragma unroll
    for (int ky=0;ky<3;ky++)
      #pragma unroll
      for (int kx=0;kx<3;kx++){
        const float wt = wv[ky*3+kx];
        s0 = __builtin_fmaf(wt, f[ky][j+kx],   s0);
        s1 = __builtin_fmaf(wt, f[ky+1][j+kx], s1);
      }
    unsigned h0 = f2bfbits(s0), h1 = f2bfbits(s1);
    if (j&1){ ow0[j>>1] |= h0<<16; ow1[j>>1] |= h1<<16; }
    else    { ow0[j>>1] = h0;      ow1[j>>1] = h1; }
  }
  const int r0 = 2*yp;
  if (ch < 2*CCH){
    *(int4*)((short*)out + (size_t)bc*NP + r0*64 + x0)     = *(int4*)&ow0[0];
    *(int4*)((short*)out + (size_t)bc*NP + (r0+1)*64 + x0) = *(int4*)&ow1[0];
  } else {
    const int chv = ch - 2*CCH;
    const int head = chv / HD, d = chv % HD;
    int4* vtb = (int4*)((short*)out + ((size_t)b*C3 + 2*CCH)*NP);
    #pragma unroll
    for (int rr=0; rr<2; rr++){
      const int u = (r0+rr)*8 + xs;
      const int hh = u&1;
      const size_t idx = ((size_t)head*32 + (u>>4))*768
                       + (((u>>2)&3)*2 + ((u>>1)&1))*96
                       + (d < 32 ? hh*32 + d : 64 + hh*16 + (d-32));
      vtb[idx] = rr ? *(int4*)&ow1[0] : *(int4*)&ow0[0];
    }
  }
}

// ---------------------------------------------------------------------------
// L2 normalize K ONLY -> KT2 (MFMA-fragment order, no padding). Q-norm is
// fused into flash's Q load. KT2 per bh: [32 chunks][768 int4]:
//   int4 idx = c*768 + s*192 + st*64 + h*32 + m
//   content  = K[key = c*128 + s*32 + m][d = st*16 + h*8 .. +8] (normalized)
// ---------------------------------------------------------------------------
__global__ __launch_bounds__(256) void l2norm_t_kernel(
    const bf16* __restrict__ buf, int4* __restrict__ KTg)
{
  int idx = blockIdx.x*256 + threadIdx.x;   // 32768 total
  int n = idx & 4095; int t = idx >> 12;    // t 0..7
  int head = t & 3; int b = t >> 2;
  const bf16* p = buf + ((size_t)b*C3 + CCH + head*HD)*NP + n;
  float v[HD];
  float ss = 0.f;
  #pragma unroll
  for (int d=0; d<HD; d++){ v[d] = bf2f(p[(size_t)d*NP]); ss += v[d]*v[d]; }
  float inv = 1.0f / fmaxf(sqrtf(ss), 1e-12f);
  const int c = n>>7, s = (n>>5)&3, mm = n&31;
  int4* kt = KTg + ((size_t)(b*NH+head)*32 + c)*768 + s*192 + mm;
  #pragma unroll
  for (int st=0; st<3; st++){
    #pragma unroll
    for (int hh=0; hh<2; hh++){
      int d0 = st*16 + hh*8;
      int4 w;
      w.x = (unsigned)f2bfbits(v[d0+0]*inv) | ((unsigned)f2bfbits(v[d0+1]*inv)<<16);
      w.y = (unsigned)f2bfbits(v[d0+2]*inv) | ((unsigned)f2bfbits(v[d0+3]*inv)<<16);
      w.z = (unsigned)f2bfbits(v[d0+4]*inv) | ((unsigned)f2bfbits(v[d0+5]*inv)<<16);
      w.w = (unsigned)f2bfbits(v[d0+6]*inv) | ((unsigned)f2bfbits(v[d0+7]*inv)<<16);
      kt[st*64 + hh*32] = w;
    }
  }
}

// ---------------------------------------------------------------------------
// Flash attention, mfma_f32_32x32x16_bf16, 512-thread blocks. Q is
// normalized INLINE at load (lane pair (m,h)/(m,h^1) holds all 48 d; one
// shfl_xor combines the two half-sums). Otherwise unchanged from R9.
// ---------------------------------------------------------------------------
#define ONES_SH 36864
__global__ __launch_bounds__(512, 4) void flash_kernel(
    const bf16* __restrict__ qkv,      // bufB [b][c3][n] (q raw, k; V = VT)
    const int4* __restrict__ KTg,      // KT2
    const bf16* __restrict__ temp,
    short* __restrict__ OT)            // [b][4096][192] bf16 bits
{
  __shared__ __align__(16) short SH[36872];   // 73744 B: ring 73728 + ones 16

  const int bh = blockIdx.x, b = bh>>2, head = bh&3;
  const int q0 = blockIdx.y * 64;
  const int tid = threadIdx.x, wave = tid>>6, lane = tid&63;
  const int m = lane & 31, h = lane >> 5;
  const int qtile = wave & 1, stream = wave >> 1;   // 4 streams x 32 keys

  const int4* KT0 = KTg + (size_t)bh*24576;                    // 32*768
  const int4* VT0 = (const int4*)(qkv + ((size_t)b*C3 + 2*CCH)*NP)
                    + (size_t)head*24576;
  const float sc = bf2f(temp[head]) * 1.44269504f;
  const float negM = -__builtin_fabsf(sc);       // fixed softmax shift

  if (tid == 0){                                  // bf16(1.0) x8 ones slot
    int4 ones; ones.x = ones.y = ones.z = ones.w = 0x3F803F80;
    *(int4*)&SH[ONES_SH] = ones;
  }

  // Q B-fragments with INLINE L2 NORM: B[q=m][d = st*16 + h*8 + j].
  // This lane holds 24 of the 48 d's; lane m+(h^1)*32 holds the rest.
  I4B8 Qf[3];
  {
    const unsigned short* Qp = (const unsigned short*)(qkv + ((size_t)b*C3 + head*HD)*NP)
                               + q0 + qtile*32 + m;
    float qf[3][8];
    float ss = 0.f;
    #pragma unroll
    for (int st=0; st<3; st++)
      #pragma unroll
      for (int j=0;j<8;j++){
        float v = bfb2f((short)Qp[(size_t)(st*16 + h*8 + j)*NP]);
        qf[st][j] = v; ss += v*v;
      }
    ss += __shfl_xor(ss, 32);
    const float inv = 1.0f / fmaxf(sqrtf(ss), 1e-12f);
    #pragma unroll
    for (int st=0; st<3; st++){
      Qf[st].i.x = (int)pkbf(qf[st][0]*inv, qf[st][1]*inv);
      Qf[st].i.y = (int)pkbf(qf[st][2]*inv, qf[st][3]*inv);
      Qf[st].i.z = (int)pkbf(qf[st][4]*inv, qf[st][5]*inv);
      Qf[st].i.w = (int)pkbf(qf[st][6]*inv, qf[st][7]*inv);
    }
  }

  f32x16 O0, O1;                     // C[q][d]: d 0..31 | d 32..47 + rowsum@48
  #pragma unroll
  for (int r=0;r<16;r++){ O0[r]=0.f; O1[r]=0.f; }

  #define ISSUE(CHUNK, BUFI) { \
    if (wave < 4){ \
      const int4* kg_ = KT0 + (size_t)(CHUNK)*768 + wave*192 + lane; \
      short* kd_ = &SH[(BUFI)*6144 + wave*1536]; \
      gl_lds16(kg_,       kd_); \
      gl_lds16(kg_ + 64,  kd_ + 512); \
      gl_lds16(kg_ + 128, kd_ + 1024); \
    } else { \
      const int4* vg_ = VT0 + (size_t)(CHUNK)*768 + (wave-4)*192 + lane; \
      short* vd_ = &SH[18432 + (BUFI)*6144 + (wave-4)*1536]; \
      gl_lds16(vg_,       vd_); \
      gl_lds16(vg_ + 64,  vd_ + 512); \
      gl_lds16(vg_ + 128, vd_ + 1024); \
    } }

  ISSUE(0, 0);
  ISSUE(1, 1);
  asm volatile("s_waitcnt vmcnt(3)" ::: "memory");
  __builtin_amdgcn_s_barrier();
  __builtin_amdgcn_sched_barrier(0);

  for (int t=0; t<32; ++t){
    const int cur = t % 3;
    if (t < 30) ISSUE(t+2, (t+2)%3);

    const short* Kb = &SH[cur*6144];
    const short* Vb = &SH[18432 + cur*6144];

    // S^T[kk][q] = mfma(A=K rows kk, B=Q rows q); lane: q=m, kk=(r&3)+8*(r>>2)+4h
    f32x16 S;
    #pragma unroll
    for (int r=0;r<16;r++) S[r] = 0.f;
    __builtin_amdgcn_s_setprio(1);
    #pragma unroll
    for (int st=0; st<3; st++){
      I4B8 A;
      A.i = *(const int4*)&Kb[(stream*192 + st*64 + lane)*8];
      S = __builtin_amdgcn_mfma_f32_32x32x16_bf16(A.v, Qf[st].v, S, 0,0,0);
    }
    __builtin_amdgcn_s_setprio(0);

    #pragma unroll
    for (int ks=0; ks<2; ks++){
      float p[8];
      #pragma unroll
      for (int j=0;j<8;j++)
        p[j] = __builtin_amdgcn_exp2f(__builtin_fmaf(S[8*ks+j], sc, negM));
      unsigned u0 = pkbf(p[0], p[1]);   // kk = 16ks+4h+{0,1}
      unsigned u1 = pkbf(p[2], p[3]);   // kk = 16ks+4h+{2,3}
      unsigned w0 = pkbf(p[4], p[5]);   // kk = 16ks+8+4h+{0,1}
      unsigned w1 = pkbf(p[6], p[7]);   // kk = 16ks+8+4h+{2,3}
      plswap(w0, u0);   // -> u0 = A dword0, w0 = A dword2
      plswap(w1, u1);   // -> u1 = A dword1, w1 = A dword3
      I4B8 PA;
      PA.i.x = (int)u0; PA.i.y = (int)u1; PA.i.z = (int)w0; PA.i.w = (int)w1;
      const int vbase = ((stream*2 + ks)*96)*8;
      I4B8 BV0, BV1;
      BV0.i = *(const int4*)&Vb[vbase + lane*8];
      const int v1s = (m < 16) ? (18432 + cur*6144 + vbase + 512 + (h*16+m)*8)
                               : ONES_SH;
      BV1.i = *(const int4*)&SH[v1s];
      __builtin_amdgcn_s_setprio(1);
      O0 = __builtin_amdgcn_mfma_f32_32x32x16_bf16(PA.v, BV0.v, O0, 0,0,0);
      O1 = __builtin_amdgcn_mfma_f32_32x32x16_bf16(PA.v, BV1.v, O1, 0,0,0);
      __builtin_amdgcn_s_setprio(0);
    }

    if (t < 30) asm volatile("s_waitcnt vmcnt(3)" ::: "memory");
    else        asm volatile("s_waitcnt vmcnt(0)" ::: "memory");
    __builtin_amdgcn_s_barrier();
    __builtin_amdgcn_sched_barrier(0);
  }
  #undef ISSUE

  // 4-way additive K-stream combine, two rounds; row-sums ride in O1.
  float* CmA = (float*)&SH[0];
  float* CmB = (float*)((char*)&SH[0] + 16896);
  if (stream >= 2){
    float* dst = (stream==2 ? CmA : CmB) + (qtile*64 + lane)*33;
    #pragma unroll
    for (int r=0;r<16;r++){ dst[r] = O0[r]; dst[16+r] = O1[r]; }
  }
  __syncthreads();
  if (stream < 2){
    const float* src = (stream==0 ? CmA : CmB) + (qtile*64 + lane)*33;
    #pragma unroll
    for (int r=0;r<16;r++){ O0[r] += src[r]; O1[r] += src[16+r]; }
  }
  __syncthreads();
  if (stream == 1){
    float* dst = CmA + (qtile*64 + lane)*33;
    #pragma unroll
    for (int r=0;r<16;r++){ dst[r] = O0[r]; dst[16+r] = O1[r]; }
  }
  __syncthreads();
  if (stream == 0){
    const float* src = CmA + (qtile*64 + lane)*33;
    #pragma unroll
    for (int r=0;r<16;r++){ O0[r] += src[r]; O1[r] += src[16+r]; }
    #pragma unroll
    for (int r=0;r<16;r++){
      const float l = __shfl(O1[r], h*32 + 16);   // rowsum column d=48
      const float inv = 1.0f / l;
      const int qr = (r&3) + 8*(r>>2) + 4*h;
      short* row = OT + ((size_t)b*NP + q0 + qtile*32 + qr)*CCH + head*HD;
      row[m] = (short)f2bfbits(O0[r]*inv);
      if (m < 16) row[32+m] = (short)f2bfbits(O1[r]*inv);
    }
  }
}

// ---------------------------------------------------------------------------
extern "C" void kernel_launch(void* const* d_in, const int* in_sizes, int n_in,
                              void* d_out, int out_size, void* d_ws, size_t ws_size,
                              hipStream_t stream)
{
  // ws layout (bytes) — 19.2 MB footprint:
  //   [0]        int flag
  //   [16]       bf16 canon[153988]
  //   [308096]   bf16 bufA[2*576*4096]  (O^T head; KT2 at byte +3145728, 3MB)
  //   [9745280]  bf16 bufB[2*576*4096]  (X^T borrows head pre-dwconv;
  //                                      V-channel region holds VT post-dwconv)
  int*  flag  = (int*)d_ws;
  bf16* canon = (bf16*)((char*)d_ws + 16);
  bf16* bufA  = (bf16*)((char*)d_ws + 308096);
  bf16* bufB  = (bf16*)((char*)d_ws + 9745280);
  short* XT = (short*)bufB;
  short* OT = (short*)bufA;
  int4*  KT = (int4*)(bufA + 1572864);

  bf16* cw_qkv  = canon;
  bf16* cb_qkv  = canon + 110592;
  bf16* cw_dw   = canon + 111168;
  bf16* cb_dw   = canon + 116352;
  bf16* cw_proj = canon + 116928;
  bf16* cb_proj = canon + 153792;
  bf16* ctemp   = canon + 153984;

  prep_kernel<<<dim3(3,64,2), 256, 0, stream>>>(d_in[0],
      d_in[1], d_in[2], d_in[3], d_in[4], d_in[5], d_in[6], d_in[7],
      flag, canon, XT);
  conv1x1_mfma_kernel<<<dim3(9,64,2), 256, 0, stream>>>(flag, 0,
      XT, cw_qkv, cb_qkv, bufA, C3);
  dwconv_kernel<<<dim3(BB*C3), 256, 0, stream>>>(bufA, cw_dw, cb_dw, bufB);
  l2norm_t_kernel<<<dim3(128), 256, 0, stream>>>(bufB, KT);
  flash_kernel<<<dim3(8,64), 512, 0, stream>>>(bufB, KT, ctemp, OT);
  conv1x1_mfma_kernel<<<dim3(3,64,2), 256, 0, stream>>>(flag, 1,
      OT, cw_proj, cb_proj, d_out, CCH);
}

// Round 12
// 154.202 us; speedup vs baseline: 1.0369x; 1.0369x over previous
//
#include <hip/hip_runtime.h>
#include <hip/hip_bf16.h>

// MDTA: prep (dtype probe + param convert + X transpose, ONE kernel) ->
// qkv 1x1 conv (MFMA GEMM 64ox128p, LDS-transposed vectorized bf16
// epilogue) -> 3x3 depthwise (zero-padded LDS image, b128 reads; V channels
// written in MFMA-fragment order "VT") -> l2norm (K-ONLY -> KT2 fragment
// order; q-norm fused into flash's Q load) -> flash attention (32x32x16
// MFMA, 512-thread blocks: 2 q-tiles x 4 K-streams, K/V staged via linear
// global_load_lds DMA (3-buffer ring, counted vmcnt), conflict-free
// stride-1 ds_read_b128, register-resident P via cvt_pk_bf16 +
// permlane32_swap, fixed-max softmax (|q.k|<=1), row-sums free via all-ones
// V column, 4-way additive K-split combine) -> 1x1 proj (MFMA GEMM).
// Input/output dtype probed at runtime; intermediates bf16 in d_ws.

#define BB 2
#define CCH 192
#define C3 576
#define NH 4
#define HD 48
#define NP 4096

typedef __hip_bfloat16 bf16;
typedef __attribute__((ext_vector_type(8))) short bf16x8;
typedef __attribute__((ext_vector_type(4))) float f32x4;
typedef __attribute__((ext_vector_type(16))) float f32x16;

union I4B8 { int4 i; bf16x8 v; };

__device__ inline float bf2f(bf16 v){ return __bfloat162float(v); }
__device__ inline unsigned short f2bfbits(float f){ return __builtin_bit_cast(unsigned short, __float2bfloat16(f)); }
__device__ inline float bfb2f(short s){ return __uint_as_float(((unsigned)(unsigned short)s)<<16); }

// pack two f32 -> dword of two bf16 (lo = first)
__device__ inline unsigned pkbf(float lo, float hi){
  unsigned r;
  asm("v_cvt_pk_bf16_f32 %0, %1, %2" : "=v"(r) : "v"(lo), "v"(hi));
  return r;
}
// swap lanes 0-31 of x with lanes 32-63 of y (both results used)
__device__ inline void plswap(unsigned &x, unsigned &y){
  asm("v_permlane32_swap_b32 %0, %1" : "+v"(x), "+v"(y));
}
// 16B global -> LDS DMA (dest = wave-uniform base + lane*16)
__device__ inline void gl_lds16(const void* g, void* l){
  __builtin_amdgcn_global_load_lds(
      (const __attribute__((address_space(1))) void*)g,
      (__attribute__((address_space(3))) void*)l, 16, 0, 0);
}

// ---------------------------------------------------------------------------
// prep: per-block dtype probe (x[0..255] dwords, L2-hot) + param convert
// (grid-strided across the 384 blocks) + X transpose -> XT [b][4096][192].
// ---------------------------------------------------------------------------
#define NCANON 153988
__global__ __launch_bounds__(256) void prep_kernel(
    const void* __restrict__ Xv,
    const void* w_qkv, const void* b_qkv, const void* w_dw, const void* b_dw,
    const void* w_proj, const void* b_proj, const void* temp,
    int* __restrict__ flag, bf16* __restrict__ canon, short* __restrict__ XT)
{
  __shared__ int cnt;
  __shared__ short T[64][66];
  const int tid = threadIdx.x;
  {
    unsigned u = ((const unsigned*)Xv)[tid];
    int e = (u >> 7) & 0xff;
    int sane = (e >= 100 && e <= 140) || ((u & 0x7fffu) == 0u);
    if (tid == 0) cnt = 0;
    __syncthreads();
    if (sane) atomicAdd(&cnt, 1);
    __syncthreads();
  }
  const bool isbf = (cnt >= 192);
  const int bid = (blockIdx.z*64 + blockIdx.y)*3 + blockIdx.x;   // 0..383
  if (bid == 0 && tid == 0) *flag = isbf ? 1 : 0;

  // param convert, grid-stride (384*256 = 98304 threads, 2 passes)
  for (int i = bid*256 + tid; i < NCANON; i += 384*256){
    const void* src; int off;
    if      (i < 110592){ src = w_qkv;  off = i; }
    else if (i < 111168){ src = b_qkv;  off = i - 110592; }
    else if (i < 116352){ src = w_dw;   off = i - 111168; }
    else if (i < 116928){ src = b_dw;   off = i - 116352; }
    else if (i < 153792){ src = w_proj; off = i - 116928; }
    else if (i < 153984){ src = b_proj; off = i - 153792; }
    else                { src = temp;   off = i - 153984; }
    float v = isbf ? bf2f(((const bf16*)src)[off]) : ((const float*)src)[off];
    canon[i] = __float2bfloat16(v);
  }

  // transpose X tile
  const int c0 = blockIdx.x*64, p0 = blockIdx.y*64, b = blockIdx.z;
  const size_t xbase = (size_t)b*CCH*NP;
  #pragma unroll
  for (int s=0;s<16;s++){
    int i = tid + s*256;
    int cc = i>>6, pp = i&63;
    size_t g = xbase + (size_t)(c0+cc)*NP + p0+pp;
    float v = isbf ? bf2f(((const bf16*)Xv)[g]) : ((const float*)Xv)[g];
    T[cc][pp] = (short)f2bfbits(v);
  }
  __syncthreads();
  #pragma unroll
  for (int s=0;s<16;s++){
    int i = tid + s*256;
    int pl = i>>6, cl = i&63;
    XT[((size_t)b*NP + p0+pl)*CCH + c0+cl] = T[cl][pl];
  }
}

// ---------------------------------------------------------------------------
// 1x1 conv as MFMA GEMM.  Block 64o x 128p, wave = 32p x 64o (R9-proven
// tile; the 64p re-tile of R11 doubled W traffic + barrier overhead and
// regressed). bf16 output: acc transposed through the (dead) Bs tile ->
// 4 coalesced int4 stores/thread.
// ---------------------------------------------------------------------------
__global__ __launch_bounds__(256) void conv1x1_mfma_kernel(
    const int* __restrict__ flag, int ydyn,
    const short* __restrict__ XT,      // [b][4096][192] bf16 bits
    const bf16* __restrict__ Wt,       // [OC][192]
    const bf16* __restrict__ bias,
    void* __restrict__ Yv, int OC)
{
  const bool yf32 = ydyn && (*flag == 0);
  __shared__ __align__(16) short Bs[2][128*32];
  const int tid = threadIdx.x, wave = tid>>6, lane = tid&63;
  const int l16 = lane&15, quad = lane>>4;
  const int o0 = blockIdx.x*64, p0 = blockIdx.y*128, b = blockIdx.z;
  const short* XTb = XT + ((size_t)b*NP + p0)*CCH;
  const short* Wb  = (const short*)Wt;

  f32x4 acc[4][2];
  #pragma unroll
  for (int mt=0;mt<4;mt++){
    #pragma unroll
    for (int r=0;r<4;r++){
      float bv = bf2f(bias[o0+mt*16+quad*4+r]);
      acc[mt][0][r]=bv; acc[mt][1][r]=bv;
    }
  }

  int4 sreg[2];
  I4B8 Afr[2][4];
  #define CLOAD(kc) { _Pragma("unroll") for (int s_=0;s_<2;s_++){ int i_=tid+256*s_; \
      sreg[s_] = *(const int4*)&XTb[(size_t)(i_>>2)*CCH + (kc)*32 + (i_&3)*8]; } }
  #define CSTORE(buf) { _Pragma("unroll") for (int s_=0;s_<2;s_++){ int i_=tid+256*s_; \
      *(int4*)&Bs[buf][(i_>>2)*32 + (i_&3)*8] = sreg[s_]; } }
  #define ALOAD(kc, buf) { _Pragma("unroll") for (int mt_=0;mt_<4;mt_++){ \
      Afr[buf][mt_].i = *(const int4*)&Wb[(size_t)(o0+mt_*16+l16)*CCH + (kc)*32 + quad*8]; } }

  CLOAD(0); CSTORE(0); ALOAD(0,0);
  __syncthreads();

  #pragma unroll
  for (int kc=0; kc<6; kc++){
    const int cur = kc&1;
    if (kc<5){ CLOAD(kc+1); ALOAD(kc+1, cur^1); }
    I4B8 Bf0, Bf1;
    Bf0.i = *(const int4*)&Bs[cur][(wave*32 + l16)*32 + quad*8];
    Bf1.i = *(const int4*)&Bs[cur][(wave*32 + 16 + l16)*32 + quad*8];
    #pragma unroll
    for (int mt=0;mt<4;mt++){
      acc[mt][0] = __builtin_amdgcn_mfma_f32_16x16x32_bf16(Afr[cur][mt].v, Bf0.v, acc[mt][0], 0,0,0);
      acc[mt][1] = __builtin_amdgcn_mfma_f32_16x16x32_bf16(Afr[cur][mt].v, Bf1.v, acc[mt][1], 0,0,0);
    }
    if (kc<5) CSTORE(cur^1);
    __syncthreads();
  }
  #undef CLOAD
  #undef CSTORE
  #undef ALOAD

  if (yf32){
    #pragma unroll
    for (int mt=0;mt<4;mt++)
      #pragma unroll
      for (int nt=0;nt<2;nt++)
        #pragma unroll
        for (int r=0;r<4;r++){
          int o = o0 + mt*16 + quad*4 + r;
          int p = p0 + wave*32 + nt*16 + l16;
          ((float*)Yv)[((size_t)b*OC + o)*NP + p] = acc[mt][nt][r];
        }
  } else {
    short* Os = &Bs[0][0];                  // 64 x 128 bf16 tile (Bs dead)
    #pragma unroll
    for (int mt=0;mt<4;mt++)
      #pragma unroll
      for (int nt=0;nt<2;nt++)
        #pragma unroll
        for (int r=0;r<4;r++)
          Os[(mt*16+quad*4+r)*128 + wave*32 + nt*16 + l16] =
              (short)f2bfbits(acc[mt][nt][r]);
    __syncthreads();
    const int o = tid>>2, xs = tid&3;
    bf16* dst = (bf16*)Yv + ((size_t)b*OC + o0 + o)*NP + p0 + xs*32;
    #pragma unroll
    for (int i=0;i<4;i++)
      *(int4*)(dst + i*8) = *(int4*)&Os[o*128 + xs*32 + i*8];
  }
}

// ---------------------------------------------------------------------------
// 3x3 depthwise conv, padding 1. One block per (b,ch) image.
// Zero-padded LDS image [66][88] (data at [y+1][8+x]); b128 reads; no
// bounds branches. q/k channels (ch < 384): linear write. V channels:
// MFMA-fragment order VT (see comments).
// ---------------------------------------------------------------------------
__global__ __launch_bounds__(256) void dwconv_kernel(
    const bf16* __restrict__ in, const bf16* __restrict__ w,
    const bf16* __restrict__ bias, bf16* __restrict__ out)
{
  __shared__ __align__(16) short img[66*88];   // 11616 B = 726 int4, padded
  const int bc = blockIdx.x; const int ch = bc % C3; const int b = bc / C3;
  const int tid = threadIdx.x;
  {
    int4 zz = {0,0,0,0};
    int4* s4 = (int4*)img;                     // 726 int4 total
    s4[tid] = zz;
    s4[tid+256] = zz;
    if (tid < 214) s4[tid+512] = zz;
  }
  float wv[9];
  #pragma unroll
  for (int j=0;j<9;j++) wv[j] = bf2f(w[ch*9+j]);
  const float bv = bf2f(bias[ch]);
  __syncthreads();
  {
    const int4* g4 = (const int4*)(in + (size_t)bc*NP);
    int i = tid;      int y = i>>3, u = i&7;
    *(int4*)&img[(y+1)*88 + 8 + u*8] = g4[i];
    i = tid+256;      y = i>>3;  u = i&7;
    *(int4*)&img[(y+1)*88 + 8 + u*8] = g4[i];
  }
  __syncthreads();

  const int yp = tid>>3, xs = tid&7, x0 = xs*8;   // rows 2yp,2yp+1; cols x0..x0+7
  float f[4][10];
  #pragma unroll
  for (int r=0;r<4;r++){
    const int base = (2*yp + r)*88 + x0;          // data col x0-8 at this addr
    short t[24];
    *(int4*)&t[0]  = *(const int4*)&img[base];
    *(int4*)&t[8]  = *(const int4*)&img[base+8];
    *(int4*)&t[16] = *(const int4*)&img[base+16];
    #pragma unroll
    for (int c=0;c<10;c++) f[r][c] = bfb2f(t[7+c]);  // data cols x0-1 .. x0+8
  }
  unsigned ow0[4], ow1[4];
  #pragma unroll
  for (int j=0;j<8;j++){
    float s0 = bv, s1 = bv;
    #pragma unroll
    for (int ky=0;ky<3;ky++)
      #pragma unroll
      for (int kx=0;kx<3;kx++){
        const float wt = wv[ky*3+kx];
        s0 = __builtin_fmaf(wt, f[ky][j+kx],   s0);
        s1 = __builtin_fmaf(wt, f[ky+1][j+kx], s1);
      }
    unsigned h0 = f2bfbits(s0), h1 = f2bfbits(s1);
    if (j&1){ ow0[j>>1] |= h0<<16; ow1[j>>1] |= h1<<16; }
    else    { ow0[j>>1] = h0;      ow1[j>>1] = h1; }
  }
  const int r0 = 2*yp;
  if (ch < 2*CCH){
    *(int4*)((short*)out + (size_t)bc*NP + r0*64 + x0)     = *(int4*)&ow0[0];
    *(int4*)((short*)out + (size_t)bc*NP + (r0+1)*64 + x0) = *(int4*)&ow1[0];
  } else {
    const int chv = ch - 2*CCH;
    const int head = chv / HD, d = chv % HD;
    int4* vtb = (int4*)((short*)out + ((size_t)b*C3 + 2*CCH)*NP);
    #pragma unroll
    for (int rr=0; rr<2; rr++){
      const int u = (r0+rr)*8 + xs;
      const int hh = u&1;
      const size_t idx = ((size_t)head*32 + (u>>4))*768
                       + (((u>>2)&3)*2 + ((u>>1)&1))*96
                       + (d < 32 ? hh*32 + d : 64 + hh*16 + (d-32));
      vtb[idx] = rr ? *(int4*)&ow1[0] : *(int4*)&ow0[0];
    }
  }
}

// ---------------------------------------------------------------------------
// L2 normalize K ONLY -> KT2 (MFMA-fragment order, no padding). Q-norm is
// fused into flash's Q load. KT2 per bh: [32 chunks][768 int4]:
//   int4 idx = c*768 + s*192 + st*64 + h*32 + m
//   content  = K[key = c*128 + s*32 + m][d = st*16 + h*8 .. +8] (normalized)
// ---------------------------------------------------------------------------
__global__ __launch_bounds__(256) void l2norm_t_kernel(
    const bf16* __restrict__ buf, int4* __restrict__ KTg)
{
  int idx = blockIdx.x*256 + threadIdx.x;   // 32768 total
  int n = idx & 4095; int t = idx >> 12;    // t 0..7
  int head = t & 3; int b = t >> 2;
  const bf16* p = buf + ((size_t)b*C3 + CCH + head*HD)*NP + n;
  float v[HD];
  float ss = 0.f;
  #pragma unroll
  for (int d=0; d<HD; d++){ v[d] = bf2f(p[(size_t)d*NP]); ss += v[d]*v[d]; }
  float inv = 1.0f / fmaxf(sqrtf(ss), 1e-12f);
  const int c = n>>7, s = (n>>5)&3, mm = n&31;
  int4* kt = KTg + ((size_t)(b*NH+head)*32 + c)*768 + s*192 + mm;
  #pragma unroll
  for (int st=0; st<3; st++){
    #pragma unroll
    for (int hh=0; hh<2; hh++){
      int d0 = st*16 + hh*8;
      int4 w;
      w.x = (unsigned)f2bfbits(v[d0+0]*inv) | ((unsigned)f2bfbits(v[d0+1]*inv)<<16);
      w.y = (unsigned)f2bfbits(v[d0+2]*inv) | ((unsigned)f2bfbits(v[d0+3]*inv)<<16);
      w.z = (unsigned)f2bfbits(v[d0+4]*inv) | ((unsigned)f2bfbits(v[d0+5]*inv)<<16);
      w.w = (unsigned)f2bfbits(v[d0+6]*inv) | ((unsigned)f2bfbits(v[d0+7]*inv)<<16);
      kt[st*64 + hh*32] = w;
    }
  }
}

// ---------------------------------------------------------------------------
// Flash attention, mfma_f32_32x32x16_bf16, 512-thread blocks. Q is
// normalized INLINE at load (lane pair (m,h)/(m,h^1) holds all 48 d; one
// shfl_xor combines the two half-sums). Otherwise unchanged from R9.
// ---------------------------------------------------------------------------
#define ONES_SH 36864
__global__ __launch_bounds__(512, 4) void flash_kernel(
    const bf16* __restrict__ qkv,      // bufB [b][c3][n] (q raw, k; V = VT)
    const int4* __restrict__ KTg,      // KT2
    const bf16* __restrict__ temp,
    short* __restrict__ OT)            // [b][4096][192] bf16 bits
{
  __shared__ __align__(16) short SH[36872];   // 73744 B: ring 73728 + ones 16

  const int bh = blockIdx.x, b = bh>>2, head = bh&3;
  const int q0 = blockIdx.y * 64;
  const int tid = threadIdx.x, wave = tid>>6, lane = tid&63;
  const int m = lane & 31, h = lane >> 5;
  const int qtile = wave & 1, stream = wave >> 1;   // 4 streams x 32 keys

  const int4* KT0 = KTg + (size_t)bh*24576;                    // 32*768
  const int4* VT0 = (const int4*)(qkv + ((size_t)b*C3 + 2*CCH)*NP)
                    + (size_t)head*24576;
  const float sc = bf2f(temp[head]) * 1.44269504f;
  const float negM = -__builtin_fabsf(sc);       // fixed softmax shift

  if (tid == 0){                                  // bf16(1.0) x8 ones slot
    int4 ones; ones.x = ones.y = ones.z = ones.w = 0x3F803F80;
    *(int4*)&SH[ONES_SH] = ones;
  }

  // Q B-fragments with INLINE L2 NORM: B[q=m][d = st*16 + h*8 + j].
  // This lane holds 24 of the 48 d's; lane m+(h^1)*32 holds the rest.
  I4B8 Qf[3];
  {
    const unsigned short* Qp = (const unsigned short*)(qkv + ((size_t)b*C3 + head*HD)*NP)
                               + q0 + qtile*32 + m;
    float qf[3][8];
    float ss = 0.f;
    #pragma unroll
    for (int st=0; st<3; st++)
      #pragma unroll
      for (int j=0;j<8;j++){
        float v = bfb2f((short)Qp[(size_t)(st*16 + h*8 + j)*NP]);
        qf[st][j] = v; ss += v*v;
      }
    ss += __shfl_xor(ss, 32);
    const float inv = 1.0f / fmaxf(sqrtf(ss), 1e-12f);
    #pragma unroll
    for (int st=0; st<3; st++){
      Qf[st].i.x = (int)pkbf(qf[st][0]*inv, qf[st][1]*inv);
      Qf[st].i.y = (int)pkbf(qf[st][2]*inv, qf[st][3]*inv);
      Qf[st].i.z = (int)pkbf(qf[st][4]*inv, qf[st][5]*inv);
      Qf[st].i.w = (int)pkbf(qf[st][6]*inv, qf[st][7]*inv);
    }
  }

  f32x16 O0, O1;                     // C[q][d]: d 0..31 | d 32..47 + rowsum@48
  #pragma unroll
  for (int r=0;r<16;r++){ O0[r]=0.f; O1[r]=0.f; }

  #define ISSUE(CHUNK, BUFI) { \
    if (wave < 4){ \
      const int4* kg_ = KT0 + (size_t)(CHUNK)*768 + wave*192 + lane; \
      short* kd_ = &SH[(BUFI)*6144 + wave*1536]; \
      gl_lds16(kg_,       kd_); \
      gl_lds16(kg_ + 64,  kd_ + 512); \
      gl_lds16(kg_ + 128, kd_ + 1024); \
    } else { \
      const int4* vg_ = VT0 + (size_t)(CHUNK)*768 + (wave-4)*192 + lane; \
      short* vd_ = &SH[18432 + (BUFI)*6144 + (wave-4)*1536]; \
      gl_lds16(vg_,       vd_); \
      gl_lds16(vg_ + 64,  vd_ + 512); \
      gl_lds16(vg_ + 128, vd_ + 1024); \
    } }

  ISSUE(0, 0);
  ISSUE(1, 1);
  asm volatile("s_waitcnt vmcnt(3)" ::: "memory");
  __builtin_amdgcn_s_barrier();
  __builtin_amdgcn_sched_barrier(0);

  for (int t=0; t<32; ++t){
    const int cur = t % 3;
    if (t < 30) ISSUE(t+2, (t+2)%3);

    const short* Kb = &SH[cur*6144];
    const short* Vb = &SH[18432 + cur*6144];

    // S^T[kk][q] = mfma(A=K rows kk, B=Q rows q); lane: q=m, kk=(r&3)+8*(r>>2)+4h
    f32x16 S;
    #pragma unroll
    for (int r=0;r<16;r++) S[r] = 0.f;
    __builtin_amdgcn_s_setprio(1);
    #pragma unroll
    for (int st=0; st<3; st++){
      I4B8 A;
      A.i = *(const int4*)&Kb[(stream*192 + st*64 + lane)*8];
      S = __builtin_amdgcn_mfma_f32_32x32x16_bf16(A.v, Qf[st].v, S, 0,0,0);
    }
    __builtin_amdgcn_s_setprio(0);

    #pragma unroll
    for (int ks=0; ks<2; ks++){
      float p[8];
      #pragma unroll
      for (int j=0;j<8;j++)
        p[j] = __builtin_amdgcn_exp2f(__builtin_fmaf(S[8*ks+j], sc, negM));
      unsigned u0 = pkbf(p[0], p[1]);   // kk = 16ks+4h+{0,1}
      unsigned u1 = pkbf(p[2], p[3]);   // kk = 16ks+4h+{2,3}
      unsigned w0 = pkbf(p[4], p[5]);   // kk = 16ks+8+4h+{0,1}
      unsigned w1 = pkbf(p[6], p[7]);   // kk = 16ks+8+4h+{2,3}
      plswap(w0, u0);   // -> u0 = A dword0, w0 = A dword2
      plswap(w1, u1);   // -> u1 = A dword1, w1 = A dword3
      I4B8 PA;
      PA.i.x = (int)u0; PA.i.y = (int)u1; PA.i.z = (int)w0; PA.i.w = (int)w1;
      const int vbase = ((stream*2 + ks)*96)*8;
      I4B8 BV0, BV1;
      BV0.i = *(const int4*)&Vb[vbase + lane*8];
      const int v1s = (m < 16) ? (18432 + cur*6144 + vbase + 512 + (h*16+m)*8)
                               : ONES_SH;
      BV1.i = *(const int4*)&SH[v1s];
      __builtin_amdgcn_s_setprio(1);
      O0 = __builtin_amdgcn_mfma_f32_32x32x16_bf16(PA.v, BV0.v, O0, 0,0,0);
      O1 = __builtin_amdgcn_mfma_f32_32x32x16_bf16(PA.v, BV1.v, O1, 0,0,0);
      __builtin_amdgcn_s_setprio(0);
    }

    if (t < 30) asm volatile("s_waitcnt vmcnt(3)" ::: "memory");
    else        asm volatile("s_waitcnt vmcnt(0)" ::: "memory");
    __builtin_amdgcn_s_barrier();
    __builtin_amdgcn_sched_barrier(0);
  }
  #undef ISSUE

  // 4-way additive K-stream combine, two rounds; row-sums ride in O1.
  float* CmA = (float*)&SH[0];
  float* CmB = (float*)((char*)&SH[0] + 16896);
  if (stream >= 2){
    float* dst = (stream==2 ? CmA : CmB) + (qtile*64 + lane)*33;
    #pragma unroll
    for (int r=0;r<16;r++){ dst[r] = O0[r]; dst[16+r] = O1[r]; }
  }
  __syncthreads();
  if (stream < 2){
    const float* src = (stream==0 ? CmA : CmB) + (qtile*64 + lane)*33;
    #pragma unroll
    for (int r=0;r<16;r++){ O0[r] += src[r]; O1[r] += src[16+r]; }
  }
  __syncthreads();
  if (stream == 1){
    float* dst = CmA + (qtile*64 + lane)*33;
    #pragma unroll
    for (int r=0;r<16;r++){ dst[r] = O0[r]; dst[16+r] = O1[r]; }
  }
  __syncthreads();
  if (stream == 0){
    const float* src = CmA + (qtile*64 + lane)*33;
    #pragma unroll
    for (int r=0;r<16;r++){ O0[r] += src[r]; O1[r] += src[16+r]; }
    #pragma unroll
    for (int r=0;r<16;r++){
      const float l = __shfl(O1[r], h*32 + 16);   // rowsum column d=48
      const float inv = 1.0f / l;
      const int qr = (r&3) + 8*(r>>2) + 4*h;
      short* row = OT + ((size_t)b*NP + q0 + qtile*32 + qr)*CCH + head*HD;
      row[m] = (short)f2bfbits(O0[r]*inv);
      if (m < 16) row[32+m] = (short)f2bfbits(O1[r]*inv);
    }
  }
}

// ---------------------------------------------------------------------------
extern "C" void kernel_launch(void* const* d_in, const int* in_sizes, int n_in,
                              void* d_out, int out_size, void* d_ws, size_t ws_size,
                              hipStream_t stream)
{
  // ws layout (bytes) — 19.2 MB footprint:
  //   [0]        int flag
  //   [16]       bf16 canon[153988]
  //   [308096]   bf16 bufA[2*576*4096]  (O^T head; KT2 at byte +3145728, 3MB)
  //   [9745280]  bf16 bufB[2*576*4096]  (X^T borrows head pre-dwconv;
  //                                      V-channel region holds VT post-dwconv)
  int*  flag  = (int*)d_ws;
  bf16* canon = (bf16*)((char*)d_ws + 16);
  bf16* bufA  = (bf16*)((char*)d_ws + 308096);
  bf16* bufB  = (bf16*)((char*)d_ws + 9745280);
  short* XT = (short*)bufB;
  short* OT = (short*)bufA;
  int4*  KT = (int4*)(bufA + 1572864);

  bf16* cw_qkv  = canon;
  bf16* cb_qkv  = canon + 110592;
  bf16* cw_dw   = canon + 111168;
  bf16* cb_dw   = canon + 116352;
  bf16* cw_proj = canon + 116928;
  bf16* cb_proj = canon + 153792;
  bf16* ctemp   = canon + 153984;

  prep_kernel<<<dim3(3,64,2), 256, 0, stream>>>(d_in[0],
      d_in[1], d_in[2], d_in[3], d_in[4], d_in[5], d_in[6], d_in[7],
      flag, canon, XT);
  conv1x1_mfma_kernel<<<dim3(9,32,2), 256, 0, stream>>>(flag, 0,
      XT, cw_qkv, cb_qkv, bufA, C3);
  dwconv_kernel<<<dim3(BB*C3), 256, 0, stream>>>(bufA, cw_dw, cb_dw, bufB);
  l2norm_t_kernel<<<dim3(128), 256, 0, stream>>>(bufB, KT);
  flash_kernel<<<dim3(8,64), 512, 0, stream>>>(bufB, KT, ctemp, OT);
  conv1x1_mfma_kernel<<<dim3(3,32,2), 256, 0, stream>>>(flag, 1,
      OT, cw_proj, cb_proj, d_out, CCH);
}